// Round 16
// baseline (607.978 us; speedup 1.0000x reference)
//
#include <hip/hip_runtime.h>
#include <cstddef>

#define HH 256
#define WW 256
#define NB 4
#define NFC 64
#define EMBC 512

typedef short s16x8 __attribute__((ext_vector_type(8)));
typedef float f32x4 __attribute__((ext_vector_type(4)));

#define GLOBAL_AS __attribute__((address_space(1)))
#define LDS_AS __attribute__((address_space(3)))

static __device__ __forceinline__ unsigned short f2b(float f) {
    unsigned int u = __float_as_uint(f);
    u += 0x7FFFu + ((u >> 16) & 1u);
    return (unsigned short)(u >> 16);
}

// ---------------------------------------------------------------------------
// Modulated weights (3 blocks in one launch) -> bf16 [b][tap][co][ci]
// ---------------------------------------------------------------------------
__global__ void modw3_kernel(
    const float* __restrict__ emb,
    const float* __restrict__ mw0, const float* __restrict__ mb0, const float* __restrict__ bw0,
    const float* __restrict__ mw1, const float* __restrict__ mb1, const float* __restrict__ bw1,
    const float* __restrict__ mw2, const float* __restrict__ mb2, const float* __restrict__ bw2,
    unsigned short* __restrict__ outw, size_t ostride)
{
    const int co = blockIdx.x, b = blockIdx.y;
    const int ci = threadIdx.x;
    const float *mw, *mb, *bw;
    switch (blockIdx.z) {
        case 0:  mw = mw0; mb = mb0; bw = bw0; break;
        case 1:  mw = mw1; mb = mb1; bw = bw1; break;
        default: mw = mw2; mb = mb2; bw = bw2; break;
    }

    const float* e = emb + (size_t)b * EMBC;
    const float* m = mw + (size_t)ci * EMBC;
    float s = mb[ci];
    for (int k = 0; k < EMBC; k += 4) {
        float4 ev = *(const float4*)(e + k);
        float4 mv = *(const float4*)(m + k);
        s += ev.x * mv.x + ev.y * mv.y + ev.z * mv.z + ev.w * mv.w;
    }

    float w[9];
    float ss = 0.f;
    const float* src = bw + ((size_t)co * NFC + ci) * 9;
#pragma unroll
    for (int k = 0; k < 9; ++k) {
        float v = (1.0f / 24.0f) * src[k] * s;
        w[k] = v;
        ss += v * v;
    }
#pragma unroll
    for (int off = 32; off; off >>= 1) ss += __shfl_xor(ss, off);
    float demod = rsqrtf(ss + 1e-8f);

    unsigned short* o = outw + (size_t)blockIdx.z * ostride;
#pragma unroll
    for (int k = 0; k < 9; ++k)
        o[(((size_t)b * 9 + k) * NFC + co) * NFC + ci] = f2b(w[k] * demod);
}

// ---------------------------------------------------------------------------
// Fixed-weight transform, 8 tensors in one launch.
// ---------------------------------------------------------------------------
__global__ void fixw8_kernel(
    const float* __restrict__ w0, const float* __restrict__ w1,
    const float* __restrict__ w2, const float* __restrict__ w3,
    const float* __restrict__ w4, const float* __restrict__ w5,
    const float* __restrict__ w6, const float* __restrict__ w7,
    unsigned short* __restrict__ wt)
{
    const int idx = blockIdx.x * 256 + threadIdx.x;
    const float* w;
    switch (blockIdx.y) {
        case 0: w = w0; break;  case 1: w = w1; break;
        case 2: w = w2; break;  case 3: w = w3; break;
        case 4: w = w4; break;  case 5: w = w5; break;
        case 6: w = w6; break;  default: w = w7; break;
    }
    const int k = idx / (NFC * NFC);
    const int rem = idx - k * (NFC * NFC);
    const int co = rem / NFC, ci = rem - co * NFC;
    wt[(size_t)blockIdx.y * 9 * NFC * NFC + idx] = f2b(w[((size_t)co * NFC + ci) * 9 + k]);
}

// ---------------------------------------------------------------------------
__global__ void fixw_last_kernel(const float* __restrict__ w, unsigned short* __restrict__ wt)
{
    int idx = blockIdx.x * 256 + threadIdx.x;
    if (idx >= 9 * 16 * NFC) return;
    int k = idx / (16 * NFC);
    int rem = idx - k * (16 * NFC);
    int co = rem / NFC, ci = rem - co * NFC;
    float v = (co < 3) ? w[((size_t)co * NFC + ci) * 9 + k] : 0.f;
    wt[idx] = f2b(v);
}

// ---------------------------------------------------------------------------
__global__ void firstw_kernel(const float* __restrict__ w, unsigned short* __restrict__ wt)
{
    int idx = blockIdx.x * 256 + threadIdx.x;   // 64*32
    if (idx >= 64 * 32) return;
    int co = idx >> 5, k = idx & 31;
    wt[idx] = (k < 27) ? f2b(w[co * 27 + k]) : 0;
}

// ---------------------------------------------------------------------------
// Layer 0 fused: halo->LDS, im2col->LDS, K=32 MFMA, bf16 NHWC out.
// ---------------------------------------------------------------------------
__global__ __launch_bounds__(256) void conv_first_fused(
    const float* __restrict__ x, const unsigned short* __restrict__ wt,
    const float* __restrict__ bias, unsigned short* __restrict__ out)
{
    __shared__ float xf[3][18][20];
    __shared__ unsigned short col[256][36];

    const int tid = threadIdx.x;
    const int flat = blockIdx.x;
    const int swz = (flat & 7) * 128 + (flat >> 3);
    const int b = swz >> 8, remb = swz & 255;
    const int h0 = (remb >> 4) * 16, w0 = (remb & 15) * 16;

    const int lane = tid & 63, wid = tid >> 6;
    const int m16 = lane & 15, kg = lane >> 4;

    s16x8 a[4];
    float4 bv[4];
#pragma unroll
    for (int mf = 0; mf < 4; ++mf) {
        a[mf] = *(const s16x8*)(wt + (mf * 16 + m16) * 32 + kg * 8);
        bv[mf] = *(const float4*)(bias + mf * 16 + kg * 4);
    }

#pragma unroll 1
    for (int idx = tid; idx < 972; idx += 256) {
        const int ci = idx / 324, rem2 = idx - ci * 324;
        const int row = rem2 / 18, colw = rem2 - row * 18;
        const int gh = h0 + row - 1, gw = w0 + colw - 1;
        float v = 0.f;
        if ((unsigned)gh < HH && (unsigned)gw < WW)
            v = x[(((size_t)b * 3 + ci) * HH + gh) * WW + gw];
        xf[ci][row][colw] = v;
    }
    __syncthreads();

    {
        const int h = tid >> 4, w = tid & 15;
        unsigned short kv[32];
#pragma unroll
        for (int ci = 0; ci < 3; ++ci)
#pragma unroll
            for (int kh = 0; kh < 3; ++kh)
#pragma unroll
                for (int kw = 0; kw < 3; ++kw)
                    kv[ci * 9 + kh * 3 + kw] = f2b(xf[ci][h + kh][w + kw]);
#pragma unroll
        for (int k = 27; k < 32; ++k) kv[k] = 0;
#pragma unroll
        for (int q = 0; q < 4; ++q)
            *(uint4*)&col[tid][q * 8] = *(const uint4*)(kv + q * 8);
    }
    __syncthreads();

#pragma unroll
    for (int t = 0; t < 4; ++t) {
        const int p = wid * 64 + t * 16 + m16;
        s16x8 bfr = *(const s16x8*)&col[p][kg * 8];
#pragma unroll
        for (int mf = 0; mf < 4; ++mf) {
            f32x4 c = (f32x4)(0.f);
            c = __builtin_amdgcn_mfma_f32_16x16x32_bf16(a[mf], bfr, c, 0, 0, 0);
            unsigned short pk[4];
#pragma unroll
            for (int e = 0; e < 4; ++e) {
                float v = c[e] + (&bv[mf].x)[e];
                v = v >= 0.f ? v : 0.1f * v;
                pk[e] = f2b(v);
            }
            const int h = h0 + (p >> 4), w = w0 + (p & 15);
            *(ushort4*)(out + (((size_t)b * HH + h) * WW + w) * NFC + mf * 16 + kg * 4)
                = *(ushort4*)pk;
        }
    }
}

// ---------------------------------------------------------------------------
// Persistent MFMA conv (round 16 = round 15 + A-in-registers):
//  - wave = NCOG co-split x row-split; main: 32co x 4rows (NCOG=2, MFW=2)
//  - A-weights in 144 VGPRs, loaded ONCE per block from global (r12 formula)
//  - amdgpu_waves_per_eu(2,2) pins occupancy target -> 256-VGPR budget
//    (fixes r12's 128-cap spill); weight-LDS and its DMA deleted
//  - B from double-buffered LDS tiles, parity prefetch; borders two-phase;
//    16B paired stores (r15 FIX 2)
// ---------------------------------------------------------------------------
template <int MFW, int NCOG, bool PERB, bool BIAS, bool LRELU, bool NOISE, bool OUTF32>
__global__ __launch_bounds__(512, 2) __attribute__((amdgpu_waves_per_eu(2, 2)))
void mconv(
    const unsigned short* __restrict__ in, const unsigned short* __restrict__ wt,
    const float* __restrict__ bias, const float* __restrict__ noise,
    const float* __restrict__ wnp, void* __restrict__ outv)
{
    constexpr int COP = MFW * 16 * NCOG;          // 64 main, 16 last
    constexpr int RPW = 16 / (8 / NCOG);          // 4 main, 2 last
    constexpr int WELEM = 9 * COP * NFC;
    __shared__ uint4 xs[2][18 * 18 * 8];          // 82944 B (no weight LDS)

    const int tid = threadIdx.x;
    const int lane = tid & 63, wid = tid >> 6;    // wid 0..7
    const int m16 = lane & 15, kg = lane >> 4;
    const int cog = wid % NCOG;                   // co-group
    const int rg = wid / NCOG;                    // row-group

    const int hw = blockIdx.x;                    // 0..255
    const int n = (hw & 7) * 32 + (hw >> 3);      // XCD-chunked logical id
    const int b = n >> 6;

    // ---- A-weights into registers, once per block (issued before staging) ----
    const unsigned short* wsrc = PERB ? wt + (size_t)b * WELEM : wt;
    s16x8 a_regs[18][MFW];
#pragma unroll
    for (int g = 0; g < 18; ++g) {
        const int tap = g >> 1, half = g & 1;
#pragma unroll
        for (int mf = 0; mf < MFW; ++mf)
            a_regs[g][mf] = *(const s16x8*)(wsrc
                + ((size_t)tap * COP + cog * MFW * 16 + mf * 16 + m16) * NFC
                + half * 32 + kg * 8);
    }

    auto stage_tile = [&](int tt, uint4* buf) {
        const int remb = tt & 255;
        const int th = remb >> 4, tw = remb & 15;
        const int h0 = th * 16, w0 = tw * 16;
        const bool interior = (th > 0) && (th < 15) && (tw > 0) && (tw < 15);
        if (interior) {
            for (int i = wid; i < 54; i += 8) {
                const int row = i / 3, part = i - row * 3;
                const int j0 = (part == 0) ? -1 : (part == 1) ? 7 : 9;
                const int gh = h0 + row - 1;
                const int j = j0 + (lane >> 3);
                const int gw = w0 + j;
                const int w = j + 1;
                const unsigned short* gp = in + (((size_t)b * HH + gh) * WW + gw) * NFC
                                              + ((lane & 7) ^ (w & 7)) * 8;
                uint4* lp = buf + (size_t)(row * 18 + (j0 + 1)) * 8;
                __builtin_amdgcn_global_load_lds(
                    (const GLOBAL_AS void*)gp, (LDS_AS void*)lp, 16, 0, 0);
            }
        } else {
            // two-phase border staging, 6 loads in flight
            uint4 u[6];
#pragma unroll
            for (int i = 0; i < 6; ++i) {
                const int idx = tid + i * 512;
                u[i] = make_uint4(0, 0, 0, 0);
                if (idx < 2592) {
                    const int row = idx / 144, rem2 = idx - row * 144;
                    const int w = rem2 >> 3, slot = rem2 & 7;
                    const int gh = h0 + row - 1, gw = w0 + w - 1;
                    if ((unsigned)gh < HH && (unsigned)gw < WW)
                        u[i] = *(const uint4*)(in + (((size_t)b * HH + gh) * WW + gw) * NFC + slot * 8);
                }
            }
#pragma unroll
            for (int i = 0; i < 6; ++i) {
                const int idx = tid + i * 512;
                if (idx < 2592) {
                    const int row = idx / 144, rem2 = idx - row * 144;
                    const int w = rem2 >> 3, slot = rem2 & 7;
                    buf[(row * 18 + w) * 8 + (slot ^ (w & 7))] = u[i];
                }
            }
        }
    };

    stage_tile(n * 4, xs[0]);
    __syncthreads();

    const float wn = NOISE ? wnp[0] : 0.f;

#pragma unroll 1
    for (int k = 0; k < 4; ++k) {
        const int tt = n * 4 + k;
        const int remb = tt & 255;
        const int h0 = (remb >> 4) * 16, w0 = (remb & 15) * 16;
        const uint4* buf = xs[k & 1];

        if (k < 3) stage_tile(tt + 1, xs[(k + 1) & 1]);

        f32x4 acc[MFW][RPW];
#pragma unroll
        for (int mf = 0; mf < MFW; ++mf)
#pragma unroll
            for (int r = 0; r < RPW; ++r) acc[mf][r] = (f32x4)(0.f);

        s16x8 bbuf[2][RPW];
        auto LOADB = [&](int g, int par) {
            const int tap = g >> 1, half = g & 1;
            const int kh = tap / 3, kw = tap - kh * 3;
            const int lw = m16 + kw;
            const int slot = (half * 4 + kg) ^ (lw & 7);
#pragma unroll
            for (int r = 0; r < RPW; ++r) {
                const int lrow = rg * RPW + r + kh;
                bbuf[par][r] = *(const s16x8*)&buf[(lrow * 18 + lw) * 8 + slot];
            }
        };

        LOADB(0, 0);
#pragma unroll
        for (int g = 0; g < 18; ++g) {
            if (g + 1 < 18) LOADB(g + 1, (g + 1) & 1);
#pragma unroll
            for (int r = 0; r < RPW; ++r)
#pragma unroll
                for (int mf = 0; mf < MFW; ++mf)
                    acc[mf][r] = __builtin_amdgcn_mfma_f32_16x16x32_bf16(
                        a_regs[g][mf], bbuf[g & 1][r], acc[mf][r], 0, 0, 0);
        }

        // ---- epilogue: wave owns rows rg*RPW..+RPW-1, co cog*MFW*16..+ ----
        const int wcol = w0 + m16;
#pragma unroll
        for (int r = 0; r < RPW; ++r) {
            const int h = h0 + rg * RPW + r;
            float nz = 0.f;
            if (NOISE) nz = noise[((size_t)b * HH + h) * WW + wcol];

            if (!OUTF32) {
                uint2 pkk[MFW];
#pragma unroll
                for (int mf = 0; mf < MFW; ++mf) {
                    const int cob = cog * MFW * 16 + mf * 16 + kg * 4;
                    f32x4 v = acc[mf][r];
                    float4 bvv = make_float4(0.f, 0.f, 0.f, 0.f);
                    if (BIAS) bvv = *(const float4*)(bias + cob);
                    unsigned short pk[4];
#pragma unroll
                    for (int e = 0; e < 4; ++e) {
                        float t = v[e] + (BIAS ? (&bvv.x)[e] : 0.f);
                        if (NOISE) t += wn * nz;
                        if (LRELU) t = t >= 0.f ? t : 0.1f * t;
                        pk[e] = f2b(t);
                    }
                    pkk[mf] = *(uint2*)pk;
                }
                // pair lanes kg <-> kg^1 (lane^16) into 16B stores
                unsigned short* ob = (unsigned short*)outv;
                unsigned short* obp = ob + (((size_t)b * HH + h) * WW + wcol) * NFC;
#pragma unroll
                for (int mf = 0; mf < MFW; ++mf) {
                    uint2 own = pkk[mf];
                    uint2 part;
                    part.x = __shfl_xor((int)own.x, 16);
                    part.y = __shfl_xor((int)own.y, 16);
                    uint2 lo = (kg & 1) ? part : own;   // co (kg&~1)*4 .. +3
                    uint2 hi = (kg & 1) ? own : part;   // co +4 .. +7
                    if ((mf & 1) == (kg & 1)) {
                        const int cob16 = cog * MFW * 16 + mf * 16 + (kg & ~1) * 4;
                        uint4 val = make_uint4(lo.x, lo.y, hi.x, hi.y);
                        *(uint4*)(obp + cob16) = val;
                    }
                }
            } else {
#pragma unroll
                for (int mf = 0; mf < MFW; ++mf) {
                    const int cob = cog * MFW * 16 + mf * 16 + kg * 4;
                    f32x4 v = acc[mf][r];
                    float4 bvv = make_float4(0.f, 0.f, 0.f, 0.f);
                    if (BIAS) bvv = *(const float4*)(bias + cob);
                    float* of = (float*)outv;
#pragma unroll
                    for (int e = 0; e < 4; ++e) {
                        float t = v[e] + (BIAS ? (&bvv.x)[e] : 0.f);
                        if (NOISE) t += wn * nz;
                        if (LRELU) t = t >= 0.f ? t : 0.1f * t;
                        int co = cob + e;
                        if (co < 3)
                            of[(((size_t)b * 3 + co) * HH + h) * WW + wcol] = t;
                    }
                }
            }
        }
        __syncthreads();
    }
}

// ---------------------------------------------------------------------------
extern "C" void kernel_launch(void* const* d_in, const int* in_sizes, int n_in,
                              void* d_out, int out_size, void* d_ws, size_t ws_size,
                              hipStream_t stream)
{
    auto F = [&](int i) { return (const float*)d_in[i]; };
    const float* x       = F(0);
    const float* emb     = F(1);
    const float* noise[3] = {F(2), F(3), F(4)};
    const float* w_first = F(5);  const float* b_first = F(6);
    const float* w_hr[5] = {F(7), F(9), F(11), F(13), F(15)};
    const float* b_hr[5] = {F(8), F(10), F(12), F(14), F(16)};
    const float* w_last  = F(17); const float* b_last = F(18);
    const float *m_mw[3], *m_mb[3], *m_w[3], *m_cw[3], *m_cb[3], *m_wn[3];
    for (int i = 0; i < 3; ++i) {
        int o = 19 + 6 * i;
        m_mw[i] = F(o); m_mb[i] = F(o + 1); m_w[i] = F(o + 2);
        m_cw[i] = F(o + 3); m_cb[i] = F(o + 4); m_wn[i] = F(o + 5);
    }

    const size_t ACT  = (size_t)NB * HH * WW * NFC;
    const size_t MODW = (size_t)NB * 9 * NFC * NFC;
    const size_t FIXW = (size_t)9 * NFC * NFC;
    unsigned short* act0 = (unsigned short*)d_ws;
    unsigned short* act1 = act0 + ACT;
    unsigned short* wmod = act1 + ACT;
    unsigned short* wfix = wmod + 3 * MODW;
    unsigned short* wlast = wfix + 8 * FIXW;
    unsigned short* wfirst = wlast + 9 * 16 * NFC;

    modw3_kernel<<<dim3(NFC, NB, 3), NFC, 0, stream>>>(
        emb, m_mw[0], m_mb[0], m_w[0], m_mw[1], m_mb[1], m_w[1],
        m_mw[2], m_mb[2], m_w[2], wmod, MODW);
    fixw8_kernel<<<dim3(144, 8), 256, 0, stream>>>(
        m_cw[0], m_cw[1], m_cw[2], w_hr[0], w_hr[1], w_hr[2], w_hr[3], w_hr[4], wfix);
    fixw_last_kernel<<<(9 * 16 * 64 + 255) / 256, 256, 0, stream>>>(w_last, wlast);
    firstw_kernel<<<8, 256, 0, stream>>>(w_first, wfirst);

    conv_first_fused<<<1024, 256, 0, stream>>>(x, wfirst, b_first, act0);

    const int grid = 256;
    unsigned short* cur = act0;
    unsigned short* nxt = act1;
    auto swap = [&]() { unsigned short* t = cur; cur = nxt; nxt = t; };

    for (int i = 0; i < 3; ++i) {
        mconv<2, 2, true, false, false, true, false>
            <<<grid, 512, 0, stream>>>(cur, wmod + i * MODW, nullptr, noise[i], m_wn[i], nxt);
        swap();
        mconv<2, 2, false, true, true, false, false>
            <<<grid, 512, 0, stream>>>(cur, wfix + i * FIXW, m_cb[i], nullptr, nullptr, nxt);
        swap();
        mconv<2, 2, false, true, false, false, false>
            <<<grid, 512, 0, stream>>>(cur, wfix + (3 + i) * FIXW, b_hr[i], nullptr, nullptr, nxt);
        swap();
    }
    mconv<2, 2, false, true, false, false, false>
        <<<grid, 512, 0, stream>>>(cur, wfix + 6 * FIXW, b_hr[3], nullptr, nullptr, nxt);
    swap();
    mconv<2, 2, false, true, false, false, false>
        <<<grid, 512, 0, stream>>>(cur, wfix + 7 * FIXW, b_hr[4], nullptr, nullptr, nxt);
    swap();
    mconv<1, 1, false, true, false, false, true>
        <<<grid, 512, 0, stream>>>(cur, wlast, b_last, nullptr, nullptr, d_out);
}

// Round 17
// 328.458 us; speedup vs baseline: 1.8510x; 1.8510x over previous
//
#include <hip/hip_runtime.h>
#include <cstddef>

#define HH 256
#define WW 256
#define NB 4
#define NFC 64
#define EMBC 512

typedef short s16x8 __attribute__((ext_vector_type(8)));
typedef float f32x4 __attribute__((ext_vector_type(4)));

#define GLOBAL_AS __attribute__((address_space(1)))
#define LDS_AS __attribute__((address_space(3)))

static __device__ __forceinline__ unsigned short f2b(float f) {
    unsigned int u = __float_as_uint(f);
    u += 0x7FFFu + ((u >> 16) & 1u);
    return (unsigned short)(u >> 16);
}

// ---------------------------------------------------------------------------
// Modulated weights (3 blocks in one launch) -> bf16 [b][tap][co][ci]
// ---------------------------------------------------------------------------
__global__ void modw3_kernel(
    const float* __restrict__ emb,
    const float* __restrict__ mw0, const float* __restrict__ mb0, const float* __restrict__ bw0,
    const float* __restrict__ mw1, const float* __restrict__ mb1, const float* __restrict__ bw1,
    const float* __restrict__ mw2, const float* __restrict__ mb2, const float* __restrict__ bw2,
    unsigned short* __restrict__ outw, size_t ostride)
{
    const int co = blockIdx.x, b = blockIdx.y;
    const int ci = threadIdx.x;
    const float *mw, *mb, *bw;
    switch (blockIdx.z) {
        case 0:  mw = mw0; mb = mb0; bw = bw0; break;
        case 1:  mw = mw1; mb = mb1; bw = bw1; break;
        default: mw = mw2; mb = mb2; bw = bw2; break;
    }

    const float* e = emb + (size_t)b * EMBC;
    const float* m = mw + (size_t)ci * EMBC;
    float s = mb[ci];
    for (int k = 0; k < EMBC; k += 4) {
        float4 ev = *(const float4*)(e + k);
        float4 mv = *(const float4*)(m + k);
        s += ev.x * mv.x + ev.y * mv.y + ev.z * mv.z + ev.w * mv.w;
    }

    float w[9];
    float ss = 0.f;
    const float* src = bw + ((size_t)co * NFC + ci) * 9;
#pragma unroll
    for (int k = 0; k < 9; ++k) {
        float v = (1.0f / 24.0f) * src[k] * s;
        w[k] = v;
        ss += v * v;
    }
#pragma unroll
    for (int off = 32; off; off >>= 1) ss += __shfl_xor(ss, off);
    float demod = rsqrtf(ss + 1e-8f);

    unsigned short* o = outw + (size_t)blockIdx.z * ostride;
#pragma unroll
    for (int k = 0; k < 9; ++k)
        o[(((size_t)b * 9 + k) * NFC + co) * NFC + ci] = f2b(w[k] * demod);
}

// ---------------------------------------------------------------------------
// Fixed-weight transform, 8 tensors in one launch.
// ---------------------------------------------------------------------------
__global__ void fixw8_kernel(
    const float* __restrict__ w0, const float* __restrict__ w1,
    const float* __restrict__ w2, const float* __restrict__ w3,
    const float* __restrict__ w4, const float* __restrict__ w5,
    const float* __restrict__ w6, const float* __restrict__ w7,
    unsigned short* __restrict__ wt)
{
    const int idx = blockIdx.x * 256 + threadIdx.x;
    const float* w;
    switch (blockIdx.y) {
        case 0: w = w0; break;  case 1: w = w1; break;
        case 2: w = w2; break;  case 3: w = w3; break;
        case 4: w = w4; break;  case 5: w = w5; break;
        case 6: w = w6; break;  default: w = w7; break;
    }
    const int k = idx / (NFC * NFC);
    const int rem = idx - k * (NFC * NFC);
    const int co = rem / NFC, ci = rem - co * NFC;
    wt[(size_t)blockIdx.y * 9 * NFC * NFC + idx] = f2b(w[((size_t)co * NFC + ci) * 9 + k]);
}

// ---------------------------------------------------------------------------
__global__ void fixw_last_kernel(const float* __restrict__ w, unsigned short* __restrict__ wt)
{
    int idx = blockIdx.x * 256 + threadIdx.x;
    if (idx >= 9 * 16 * NFC) return;
    int k = idx / (16 * NFC);
    int rem = idx - k * (16 * NFC);
    int co = rem / NFC, ci = rem - co * NFC;
    float v = (co < 3) ? w[((size_t)co * NFC + ci) * 9 + k] : 0.f;
    wt[idx] = f2b(v);
}

// ---------------------------------------------------------------------------
__global__ void firstw_kernel(const float* __restrict__ w, unsigned short* __restrict__ wt)
{
    int idx = blockIdx.x * 256 + threadIdx.x;   // 64*32
    if (idx >= 64 * 32) return;
    int co = idx >> 5, k = idx & 31;
    wt[idx] = (k < 27) ? f2b(w[co * 27 + k]) : 0;
}

// ---------------------------------------------------------------------------
// Layer 0 fused: halo->LDS, im2col->LDS, K=32 MFMA, bf16 NHWC out.
// ---------------------------------------------------------------------------
__global__ __launch_bounds__(256) void conv_first_fused(
    const float* __restrict__ x, const unsigned short* __restrict__ wt,
    const float* __restrict__ bias, unsigned short* __restrict__ out)
{
    __shared__ float xf[3][18][20];
    __shared__ unsigned short col[256][36];

    const int tid = threadIdx.x;
    const int flat = blockIdx.x;
    const int swz = (flat & 7) * 128 + (flat >> 3);
    const int b = swz >> 8, remb = swz & 255;
    const int h0 = (remb >> 4) * 16, w0 = (remb & 15) * 16;

    const int lane = tid & 63, wid = tid >> 6;
    const int m16 = lane & 15, kg = lane >> 4;

    s16x8 a[4];
    float4 bv[4];
#pragma unroll
    for (int mf = 0; mf < 4; ++mf) {
        a[mf] = *(const s16x8*)(wt + (mf * 16 + m16) * 32 + kg * 8);
        bv[mf] = *(const float4*)(bias + mf * 16 + kg * 4);
    }

#pragma unroll 1
    for (int idx = tid; idx < 972; idx += 256) {
        const int ci = idx / 324, rem2 = idx - ci * 324;
        const int row = rem2 / 18, colw = rem2 - row * 18;
        const int gh = h0 + row - 1, gw = w0 + colw - 1;
        float v = 0.f;
        if ((unsigned)gh < HH && (unsigned)gw < WW)
            v = x[(((size_t)b * 3 + ci) * HH + gh) * WW + gw];
        xf[ci][row][colw] = v;
    }
    __syncthreads();

    {
        const int h = tid >> 4, w = tid & 15;
        unsigned short kv[32];
#pragma unroll
        for (int ci = 0; ci < 3; ++ci)
#pragma unroll
            for (int kh = 0; kh < 3; ++kh)
#pragma unroll
                for (int kw = 0; kw < 3; ++kw)
                    kv[ci * 9 + kh * 3 + kw] = f2b(xf[ci][h + kh][w + kw]);
#pragma unroll
        for (int k = 27; k < 32; ++k) kv[k] = 0;
#pragma unroll
        for (int q = 0; q < 4; ++q)
            *(uint4*)&col[tid][q * 8] = *(const uint4*)(kv + q * 8);
    }
    __syncthreads();

#pragma unroll
    for (int t = 0; t < 4; ++t) {
        const int p = wid * 64 + t * 16 + m16;
        s16x8 bfr = *(const s16x8*)&col[p][kg * 8];
#pragma unroll
        for (int mf = 0; mf < 4; ++mf) {
            f32x4 c = (f32x4)(0.f);
            c = __builtin_amdgcn_mfma_f32_16x16x32_bf16(a[mf], bfr, c, 0, 0, 0);
            unsigned short pk[4];
#pragma unroll
            for (int e = 0; e < 4; ++e) {
                float v = c[e] + (&bv[mf].x)[e];
                v = v >= 0.f ? v : 0.1f * v;
                pk[e] = f2b(v);
            }
            const int h = h0 + (p >> 4), w = w0 + (p & 15);
            *(ushort4*)(out + (((size_t)b * HH + h) * WW + w) * NFC + mf * 16 + kg * 4)
                = *(ushort4*)pk;
        }
    }
}

// ---------------------------------------------------------------------------
// Persistent MFMA conv (final = round 15):
//  - 256 blocks, 1/CU; block owns 4 tiles; weights in LDS; tiles dbuf'd
//  - 512 thr = 8 waves (2/SIMD); wave = 64co x 2 rows; g+1 parity prefetch
//  - border staging two-phase (6 loads in flight)
//  - epilogue 16B stores via lane^16 pairing
// Note (r12/r13/r16): hipcc caps 512-thr blocks at 128 VGPR/thread; any
// design holding >~100 persistent VGPRs spills to scratch. A stays in LDS.
// ---------------------------------------------------------------------------
template <int MFRAGS, bool PERB, bool BIAS, bool LRELU, bool NOISE, bool OUTF32>
__global__ __launch_bounds__(512, 1) void mconv(
    const unsigned short* __restrict__ in, const unsigned short* __restrict__ wt,
    const float* __restrict__ bias, const float* __restrict__ noise,
    const float* __restrict__ wnp, void* __restrict__ outv)
{
    constexpr int COP = MFRAGS * 16;
    constexpr int WELEM = 9 * COP * NFC;
    constexpr int NWDMA = WELEM * 2 / 1024;
    __shared__ unsigned short wl[WELEM];          // 73728 B (COP=64)
    __shared__ uint4 xs[2][18 * 18 * 8];          // 82944 B

    const int tid = threadIdx.x;
    const int lane = tid & 63, wid = tid >> 6;    // wid 0..7
    const int m16 = lane & 15, kg = lane >> 4;

    const int hw = blockIdx.x;                    // 0..255
    const int n = (hw & 7) * 32 + (hw >> 3);      // XCD-chunked logical id
    const int b = n >> 6;

    // ---- stage weights once ----
    const unsigned short* wsrc = PERB ? wt + (size_t)b * WELEM : wt;
    for (int i = wid; i < NWDMA; i += 8) {
        const unsigned short* gp = wsrc + i * 512 + (lane >> 3) * 64
                                   + (((lane & 7) ^ (lane >> 3)) << 3);
        __builtin_amdgcn_global_load_lds(
            (const GLOBAL_AS void*)gp, (LDS_AS void*)(wl + i * 512), 16, 0, 0);
    }

    auto stage_tile = [&](int tt, uint4* buf) {
        const int remb = tt & 255;
        const int th = remb >> 4, tw = remb & 15;
        const int h0 = th * 16, w0 = tw * 16;
        const bool interior = (th > 0) && (th < 15) && (tw > 0) && (tw < 15);
        if (interior) {
            for (int i = wid; i < 54; i += 8) {
                const int row = i / 3, part = i - row * 3;
                const int j0 = (part == 0) ? -1 : (part == 1) ? 7 : 9;
                const int gh = h0 + row - 1;
                const int j = j0 + (lane >> 3);
                const int gw = w0 + j;
                const int w = j + 1;
                const unsigned short* gp = in + (((size_t)b * HH + gh) * WW + gw) * NFC
                                              + ((lane & 7) ^ (w & 7)) * 8;
                uint4* lp = buf + (size_t)(row * 18 + (j0 + 1)) * 8;
                __builtin_amdgcn_global_load_lds(
                    (const GLOBAL_AS void*)gp, (LDS_AS void*)lp, 16, 0, 0);
            }
        } else {
            // two-phase border staging, 6 loads in flight
            uint4 u[6];
#pragma unroll
            for (int i = 0; i < 6; ++i) {
                const int idx = tid + i * 512;
                u[i] = make_uint4(0, 0, 0, 0);
                if (idx < 2592) {
                    const int row = idx / 144, rem2 = idx - row * 144;
                    const int w = rem2 >> 3, slot = rem2 & 7;
                    const int gh = h0 + row - 1, gw = w0 + w - 1;
                    if ((unsigned)gh < HH && (unsigned)gw < WW)
                        u[i] = *(const uint4*)(in + (((size_t)b * HH + gh) * WW + gw) * NFC + slot * 8);
                }
            }
#pragma unroll
            for (int i = 0; i < 6; ++i) {
                const int idx = tid + i * 512;
                if (idx < 2592) {
                    const int row = idx / 144, rem2 = idx - row * 144;
                    const int w = rem2 >> 3, slot = rem2 & 7;
                    buf[(row * 18 + w) * 8 + (slot ^ (w & 7))] = u[i];
                }
            }
        }
    };

    stage_tile(n * 4, xs[0]);
    __syncthreads();

    const float wn = NOISE ? wnp[0] : 0.f;

#pragma unroll 1
    for (int k = 0; k < 4; ++k) {
        const int tt = n * 4 + k;
        const int remb = tt & 255;
        const int h0 = (remb >> 4) * 16, w0 = (remb & 15) * 16;
        const uint4* buf = xs[k & 1];

        if (k < 3) stage_tile(tt + 1, xs[(k + 1) & 1]);

        f32x4 acc[MFRAGS][2];
#pragma unroll
        for (int mf = 0; mf < MFRAGS; ++mf)
#pragma unroll
            for (int r = 0; r < 2; ++r) acc[mf][r] = (f32x4)(0.f);

        s16x8 abuf[2][MFRAGS];
        s16x8 bbuf[2][2];

        auto LOADG = [&](int g, int par) {
            const int tap = g >> 1, half = g & 1;
            const int kh = tap / 3, kw = tap - kh * 3;
            const int lw = m16 + kw;
            const int slot = (half * 4 + kg) ^ (lw & 7);
#pragma unroll
            for (int mf = 0; mf < MFRAGS; ++mf) {
                const int eoff = (tap * COP + mf * 16 + m16) * NFC
                                 + (((half * 4 + kg) * 8) ^ ((m16 & 7) << 3));
                abuf[par][mf] = *(const s16x8*)(wl + eoff);
            }
#pragma unroll
            for (int r = 0; r < 2; ++r) {
                const int lrow = wid * 2 + r + kh;
                bbuf[par][r] = *(const s16x8*)&buf[(lrow * 18 + lw) * 8 + slot];
            }
        };

        LOADG(0, 0);
#pragma unroll
        for (int g = 0; g < 18; ++g) {
            if (g + 1 < 18) LOADG(g + 1, (g + 1) & 1);
#pragma unroll
            for (int r = 0; r < 2; ++r)
#pragma unroll
                for (int mf = 0; mf < MFRAGS; ++mf)
                    acc[mf][r] = __builtin_amdgcn_mfma_f32_16x16x32_bf16(
                        abuf[g & 1][mf], bbuf[g & 1][r], acc[mf][r], 0, 0, 0);
        }

        // ---- epilogue: wave owns rows wid*2, wid*2+1 ----
        const int wcol = w0 + m16;
#pragma unroll
        for (int r = 0; r < 2; ++r) {
            const int h = h0 + wid * 2 + r;
            float nz = 0.f;
            if (NOISE) nz = noise[((size_t)b * HH + h) * WW + wcol];

            if (!OUTF32) {
                // pack all mf first
                uint2 pkk[MFRAGS];
#pragma unroll
                for (int mf = 0; mf < MFRAGS; ++mf) {
                    const int cob = mf * 16 + kg * 4;
                    f32x4 v = acc[mf][r];
                    float4 bvv = make_float4(0.f, 0.f, 0.f, 0.f);
                    if (BIAS) bvv = *(const float4*)(bias + cob);
                    unsigned short pk[4];
#pragma unroll
                    for (int e = 0; e < 4; ++e) {
                        float t = v[e] + (BIAS ? (&bvv.x)[e] : 0.f);
                        if (NOISE) t += wn * nz;
                        if (LRELU) t = t >= 0.f ? t : 0.1f * t;
                        pk[e] = f2b(t);
                    }
                    pkk[mf] = *(uint2*)pk;
                }
                // pair lanes kg <-> kg^1 (lane^16) into 16B stores
                unsigned short* ob = (unsigned short*)outv;
                unsigned short* obp = ob + (((size_t)b * HH + h) * WW + wcol) * NFC;
#pragma unroll
                for (int mf = 0; mf < MFRAGS; ++mf) {
                    uint2 own = pkk[mf];
                    uint2 part;
                    part.x = __shfl_xor((int)own.x, 16);
                    part.y = __shfl_xor((int)own.y, 16);
                    uint2 lo = (kg & 1) ? part : own;   // co (kg&~1)*4 .. +3
                    uint2 hi = (kg & 1) ? own : part;   // co +4 .. +7
                    if (((mf >> 1) & 1) == (kg & 1)) {
                        const int cob16 = mf * 16 + (kg & ~1) * 4;
                        uint4 val = make_uint4(lo.x, lo.y, hi.x, hi.y);
                        *(uint4*)(obp + cob16) = val;
                    }
                }
            } else {
#pragma unroll
                for (int mf = 0; mf < MFRAGS; ++mf) {
                    const int cob = mf * 16 + kg * 4;
                    f32x4 v = acc[mf][r];
                    float4 bvv = make_float4(0.f, 0.f, 0.f, 0.f);
                    if (BIAS) bvv = *(const float4*)(bias + cob);
                    float* of = (float*)outv;
#pragma unroll
                    for (int e = 0; e < 4; ++e) {
                        float t = v[e] + (BIAS ? (&bvv.x)[e] : 0.f);
                        if (NOISE) t += wn * nz;
                        if (LRELU) t = t >= 0.f ? t : 0.1f * t;
                        int co = cob + e;
                        if (co < 3)
                            of[(((size_t)b * 3 + co) * HH + h) * WW + wcol] = t;
                    }
                }
            }
        }
        __syncthreads();
    }
}

// ---------------------------------------------------------------------------
extern "C" void kernel_launch(void* const* d_in, const int* in_sizes, int n_in,
                              void* d_out, int out_size, void* d_ws, size_t ws_size,
                              hipStream_t stream)
{
    auto F = [&](int i) { return (const float*)d_in[i]; };
    const float* x       = F(0);
    const float* emb     = F(1);
    const float* noise[3] = {F(2), F(3), F(4)};
    const float* w_first = F(5);  const float* b_first = F(6);
    const float* w_hr[5] = {F(7), F(9), F(11), F(13), F(15)};
    const float* b_hr[5] = {F(8), F(10), F(12), F(14), F(16)};
    const float* w_last  = F(17); const float* b_last = F(18);
    const float *m_mw[3], *m_mb[3], *m_w[3], *m_cw[3], *m_cb[3], *m_wn[3];
    for (int i = 0; i < 3; ++i) {
        int o = 19 + 6 * i;
        m_mw[i] = F(o); m_mb[i] = F(o + 1); m_w[i] = F(o + 2);
        m_cw[i] = F(o + 3); m_cb[i] = F(o + 4); m_wn[i] = F(o + 5);
    }

    const size_t ACT  = (size_t)NB * HH * WW * NFC;
    const size_t MODW = (size_t)NB * 9 * NFC * NFC;
    const size_t FIXW = (size_t)9 * NFC * NFC;
    unsigned short* act0 = (unsigned short*)d_ws;
    unsigned short* act1 = act0 + ACT;
    unsigned short* wmod = act1 + ACT;
    unsigned short* wfix = wmod + 3 * MODW;
    unsigned short* wlast = wfix + 8 * FIXW;
    unsigned short* wfirst = wlast + 9 * 16 * NFC;

    modw3_kernel<<<dim3(NFC, NB, 3), NFC, 0, stream>>>(
        emb, m_mw[0], m_mb[0], m_w[0], m_mw[1], m_mb[1], m_w[1],
        m_mw[2], m_mb[2], m_w[2], wmod, MODW);
    fixw8_kernel<<<dim3(144, 8), 256, 0, stream>>>(
        m_cw[0], m_cw[1], m_cw[2], w_hr[0], w_hr[1], w_hr[2], w_hr[3], w_hr[4], wfix);
    fixw_last_kernel<<<(9 * 16 * 64 + 255) / 256, 256, 0, stream>>>(w_last, wlast);
    firstw_kernel<<<8, 256, 0, stream>>>(w_first, wfirst);

    conv_first_fused<<<1024, 256, 0, stream>>>(x, wfirst, b_first, act0);

    const int grid = 256;
    unsigned short* cur = act0;
    unsigned short* nxt = act1;
    auto swap = [&]() { unsigned short* t = cur; cur = nxt; nxt = t; };

    for (int i = 0; i < 3; ++i) {
        mconv<4, true, false, false, true, false>
            <<<grid, 512, 0, stream>>>(cur, wmod + i * MODW, nullptr, noise[i], m_wn[i], nxt);
        swap();
        mconv<4, false, true, true, false, false>
            <<<grid, 512, 0, stream>>>(cur, wfix + i * FIXW, m_cb[i], nullptr, nullptr, nxt);
        swap();
        mconv<4, false, true, false, false, false>
            <<<grid, 512, 0, stream>>>(cur, wfix + (3 + i) * FIXW, b_hr[i], nullptr, nullptr, nxt);
        swap();
    }
    mconv<4, false, true, false, false, false>
        <<<grid, 512, 0, stream>>>(cur, wfix + 6 * FIXW, b_hr[3], nullptr, nullptr, nxt);
    swap();
    mconv<4, false, true, false, false, false>
        <<<grid, 512, 0, stream>>>(cur, wfix + 7 * FIXW, b_hr[4], nullptr, nullptr, nxt);
    swap();
    mconv<1, false, true, false, false, true>
        <<<grid, 512, 0, stream>>>(cur, wlast, b_last, nullptr, nullptr, d_out);
}